// Round 1
// baseline (268.460 us; speedup 1.0000x reference)
//
#include <hip/hip_runtime.h>

// BilinearSampler: img [B,H,W,C] f32, x_s/y_s [B,H,W] f32 in [-1,1] -> out [B,H,W,C] f32
// B=16, H=256, W=256, C=32.
// Mapping: 8 threads per pixel, each thread handles one float4 channel group.
// Wave of 64 lanes = 8 consecutive pixels * full C -> coalesced 1 KiB store.
// R3: 4 pixel-groups per thread, software-pipelined (16 gather loads in flight).
// R4: XCD-aware block swizzle. Gathers from a block only touch image b=pix>>16
//     (8 MB footprint). Default round-robin dispatch spreads consecutive blocks
//     across all 8 XCDs -> every XCD L2 (4 MB) sees random reads over ~2-3
//     active images (16-24 MB) -> low hit rate, 221 MB HBM fetch vs 142 ideal.
//     Bijective remap bid -> (bid&7)*1024 + (bid>>3) gives each XCD a
//     contiguous 1024-block chunk = exactly 2 batch images, so each XCD
//     gathers from ~one 8 MB image at a time against its private L2, and each
//     image is streamed by exactly one XCD (better L3 residency).

constexpr int Bn = 16;
constexpr int Hn = 256;
constexpr int Wn = 256;
constexpr int Cn = 32;
constexpr int CG = Cn / 4;   // 8 float4 groups per pixel
constexpr int NP = 4;        // pixel-groups per thread

constexpr int NXCD = 8;
constexpr int GRID = (Bn * Hn * Wn) / 128;        // 8192 blocks
constexpr int CHUNK = GRID / NXCD;                // 1024 blocks per XCD

typedef float f4 __attribute__((ext_vector_type(4)));

__global__ __launch_bounds__(256) void bilinear_kernel(
    const float* __restrict__ img,
    const float* __restrict__ xs,
    const float* __restrict__ ys,
    float* __restrict__ out)
{
    const int tid = threadIdx.x;
    const int cg  = tid & 7;          // channel group (float4 index)
    const int lp  = tid >> 3;         // local pixel 0..31

    // XCD-aware bijective swizzle: XCD k (= bid % 8) gets contiguous work
    // chunk [k*CHUNK, (k+1)*CHUNK) -> images 2k and 2k+1 only.
    const int bid = blockIdx.x;
    const int wid = (bid & (NXCD - 1)) * CHUNK + (bid >> 3);

    // block covers 128 consecutive pixels as 4 chunks of 32
    const int base_pix = wid * 128 + lp;

    int pix[NP];
    float xsv[NP], ysv[NP];
#pragma unroll
    for (int g = 0; g < NP; ++g) {
        pix[g] = base_pix + g * 32;
        xsv[g] = __builtin_nontemporal_load(xs + pix[g]);
        ysv[g] = __builtin_nontemporal_load(ys + pix[g]);
    }

    float wa[NP], wb[NP], wc[NP], wd[NP];
    const f4* pa[NP];
    const f4* pb[NP];
    const f4* pc[NP];
    const f4* pd[NP];

#pragma unroll
    for (int g = 0; g < NP; ++g) {
        const float x = 0.5f * (xsv[g] + 1.0f) * (float)(Wn - 1);
        const float y = 0.5f * (ysv[g] + 1.0f) * (float)(Hn - 1);

        const int x0 = (int)floorf(x);
        const int y0 = (int)floorf(y);

        const int x0c = min(max(x0, 0), Wn - 1);
        const int x1c = min(max(x0 + 1, 0), Wn - 1);
        const int y0c = min(max(y0, 0), Hn - 1);
        const int y1c = min(max(y0 + 1, 0), Hn - 1);

        const float wx1 = (float)x1c - x;
        const float wx0 = x - (float)x0c;
        const float wy1 = (float)y1c - y;
        const float wy0 = y - (float)y0c;

        wa[g] = wx1 * wy1;
        wb[g] = wx1 * wy0;
        wc[g] = wx0 * wy1;
        wd[g] = wx0 * wy0;

        const int b = pix[g] >> 16;  // H*W = 65536
        const size_t imgbase = (size_t)b * (size_t)(Hn * Wn * Cn);

        pa[g] = (const f4*)(img + imgbase + ((size_t)(y0c * Wn + x0c)) * Cn) + cg;
        pb[g] = (const f4*)(img + imgbase + ((size_t)(y1c * Wn + x0c)) * Cn) + cg;
        pc[g] = (const f4*)(img + imgbase + ((size_t)(y0c * Wn + x1c)) * Cn) + cg;
        pd[g] = (const f4*)(img + imgbase + ((size_t)(y1c * Wn + x1c)) * Cn) + cg;
    }

    // issue all 16 gather loads before consuming any
    f4 va[NP], vb[NP], vc[NP], vd[NP];
#pragma unroll
    for (int g = 0; g < NP; ++g) {
        va[g] = *pa[g];
        vb[g] = *pb[g];
        vc[g] = *pc[g];
        vd[g] = *pd[g];
    }

#pragma unroll
    for (int g = 0; g < NP; ++g) {
        f4 o;
        o.x = wa[g] * va[g].x + wb[g] * vb[g].x + wc[g] * vc[g].x + wd[g] * vd[g].x;
        o.y = wa[g] * va[g].y + wb[g] * vb[g].y + wc[g] * vc[g].y + wd[g] * vd[g].y;
        o.z = wa[g] * va[g].z + wb[g] * vb[g].z + wc[g] * vc[g].z + wd[g] * vd[g].z;
        o.w = wa[g] * va[g].w + wb[g] * vb[g].w + wc[g] * vc[g].w + wd[g] * vd[g].w;

        f4* op = (f4*)out + (size_t)pix[g] * CG + cg;
        __builtin_nontemporal_store(o, op);
    }
}

extern "C" void kernel_launch(void* const* d_in, const int* in_sizes, int n_in,
                              void* d_out, int out_size, void* d_ws, size_t ws_size,
                              hipStream_t stream)
{
    const float* img = (const float*)d_in[0];
    const float* xs  = (const float*)d_in[1];
    const float* ys  = (const float*)d_in[2];
    float* out       = (float*)d_out;

    bilinear_kernel<<<GRID, 256, 0, stream>>>(img, xs, ys, out);
}

// Round 2
// 245.467 us; speedup vs baseline: 1.0937x; 1.0937x over previous
//
#include <hip/hip_runtime.h>

// BilinearSampler: img [B,H,W,C] f32, x_s/y_s [B,H,W] f32 in [-1,1] -> out [B,H,W,C] f32
// B=16, H=256, W=256, C=32.
// Mapping: 8 threads per pixel, each thread handles one float4 channel group.
// Wave of 64 lanes = 8 consecutive pixels * full C -> coalesced 1 KiB store.
// R3: 4 pixel-groups per thread, software-pipelined (16 gather loads in flight).
// R4 (REVERTED): XCD swizzle cut FETCH 221->157 MB but regressed 88->105 us.
//     Default dispatch already keeps the whole machine on one image at a time
//     (512 consecutive blocks per image), which is optimal for L3 + all-L2
//     sharing. Traffic is not the limiter.
// R5: force the pipeline the R3 source intended. VGPR_Count=36 proved the
//     compiler sank the 16 gather loads next to their uses (16 in-flight
//     dwordx4 need 64 live dest VGPRs) -> real MLP ~6/thread, latency-bound
//     at 4.08 TB/s with VALUBusy 14%. sched_barrier(0) between the issue
//     loop and the consume loop forces all 16 loads in flight per thread.
//     Predict: VGPR >= 96, occupancy ~55%, dur 88 -> ~65-72 us if
//     MLP-bound; unchanged if at the random-access service-rate wall.

constexpr int Bn = 16;
constexpr int Hn = 256;
constexpr int Wn = 256;
constexpr int Cn = 32;
constexpr int CG = Cn / 4;   // 8 float4 groups per pixel
constexpr int NP = 4;        // pixel-groups per thread

typedef float f4 __attribute__((ext_vector_type(4)));

__global__ __launch_bounds__(256) void bilinear_kernel(
    const float* __restrict__ img,
    const float* __restrict__ xs,
    const float* __restrict__ ys,
    float* __restrict__ out)
{
    const int tid = threadIdx.x;
    const int cg  = tid & 7;          // channel group (float4 index)
    const int lp  = tid >> 3;         // local pixel 0..31
    // block covers 128 consecutive pixels as 4 chunks of 32
    const int base_pix = blockIdx.x * 128 + lp;

    int pix[NP];
    float xsv[NP], ysv[NP];
#pragma unroll
    for (int g = 0; g < NP; ++g) {
        pix[g] = base_pix + g * 32;
        xsv[g] = __builtin_nontemporal_load(xs + pix[g]);
        ysv[g] = __builtin_nontemporal_load(ys + pix[g]);
    }

    float wa[NP], wb[NP], wc[NP], wd[NP];
    const f4* pa[NP];
    const f4* pb[NP];
    const f4* pc[NP];
    const f4* pd[NP];

#pragma unroll
    for (int g = 0; g < NP; ++g) {
        const float x = 0.5f * (xsv[g] + 1.0f) * (float)(Wn - 1);
        const float y = 0.5f * (ysv[g] + 1.0f) * (float)(Hn - 1);

        const int x0 = (int)floorf(x);
        const int y0 = (int)floorf(y);

        const int x0c = min(max(x0, 0), Wn - 1);
        const int x1c = min(max(x0 + 1, 0), Wn - 1);
        const int y0c = min(max(y0, 0), Hn - 1);
        const int y1c = min(max(y0 + 1, 0), Hn - 1);

        const float wx1 = (float)x1c - x;
        const float wx0 = x - (float)x0c;
        const float wy1 = (float)y1c - y;
        const float wy0 = y - (float)y0c;

        wa[g] = wx1 * wy1;
        wb[g] = wx1 * wy0;
        wc[g] = wx0 * wy1;
        wd[g] = wx0 * wy0;

        const int b = pix[g] >> 16;  // H*W = 65536
        const size_t imgbase = (size_t)b * (size_t)(Hn * Wn * Cn);

        pa[g] = (const f4*)(img + imgbase + ((size_t)(y0c * Wn + x0c)) * Cn) + cg;
        pb[g] = (const f4*)(img + imgbase + ((size_t)(y1c * Wn + x0c)) * Cn) + cg;
        pc[g] = (const f4*)(img + imgbase + ((size_t)(y0c * Wn + x1c)) * Cn) + cg;
        pd[g] = (const f4*)(img + imgbase + ((size_t)(y1c * Wn + x1c)) * Cn) + cg;
    }

    // issue all 16 gather loads before consuming any
    f4 va[NP], vb[NP], vc[NP], vd[NP];
#pragma unroll
    for (int g = 0; g < NP; ++g) {
        va[g] = *pa[g];
        vb[g] = *pb[g];
        vc[g] = *pc[g];
        vd[g] = *pd[g];
    }

    // Hard scheduling fence: nothing crosses. Forces all 16 loads issued
    // (and their 64 dest VGPRs live) before the first FMA consumes any.
    __builtin_amdgcn_sched_barrier(0);

#pragma unroll
    for (int g = 0; g < NP; ++g) {
        f4 o;
        o.x = wa[g] * va[g].x + wb[g] * vb[g].x + wc[g] * vc[g].x + wd[g] * vd[g].x;
        o.y = wa[g] * va[g].y + wb[g] * vb[g].y + wc[g] * vc[g].y + wd[g] * vd[g].y;
        o.z = wa[g] * va[g].z + wb[g] * vb[g].z + wc[g] * vc[g].z + wd[g] * vd[g].z;
        o.w = wa[g] * va[g].w + wb[g] * vb[g].w + wc[g] * vc[g].w + wd[g] * vd[g].w;

        f4* op = (f4*)out + (size_t)pix[g] * CG + cg;
        __builtin_nontemporal_store(o, op);
    }
}

extern "C" void kernel_launch(void* const* d_in, const int* in_sizes, int n_in,
                              void* d_out, int out_size, void* d_ws, size_t ws_size,
                              hipStream_t stream)
{
    const float* img = (const float*)d_in[0];
    const float* xs  = (const float*)d_in[1];
    const float* ys  = (const float*)d_in[2];
    float* out       = (float*)d_out;

    const int total_pixels = Bn * Hn * Wn;        // 1,048,576
    const int block = 256;
    const int grid  = total_pixels / 128;         // 8192 blocks, 128 px/block

    bilinear_kernel<<<grid, block, 0, stream>>>(img, xs, ys, out);
}